// Round 7
// baseline (164.506 us; speedup 1.0000x reference)
//
#include <hip/hip_runtime.h>
#include <cstdint>

#define B_ 16
#define S_ 1024
#define D_ 512
#define TILE 128
#define BK 32
#define PITCH 36   // legacy-path LDS pitch

typedef float f32x4 __attribute__((ext_vector_type(4)));
typedef short s16x8 __attribute__((ext_vector_type(8)));
typedef unsigned short u16;
typedef unsigned int u32;

__device__ __forceinline__ u16 f2bf(float f) {
    u32 u = __builtin_bit_cast(u32, f);
    u += 0x7FFFu + ((u >> 16) & 1u);
    return (u16)(u >> 16);
}

#define GLD16(g, l) __builtin_amdgcn_global_load_lds( \
    (const __attribute__((address_space(1))) u32*)(g), \
    (__attribute__((address_space(3))) u32*)(l), 16, 0, 0)

// ===== prep: cvt(Q) + cvt(K) + transpose-cvt(V) in one launch =====
#define TP 66
__global__ __launch_bounds__(256) void prep_kernel(const float* __restrict__ q,
                                                   const float* __restrict__ k,
                                                   const float* __restrict__ v,
                                                   u16* __restrict__ Qb,
                                                   u16* __restrict__ Kb,
                                                   u16* __restrict__ Vt) {
    __shared__ u16 t[64 * TP];
    const int bid = blockIdx.x;
    const int tid = threadIdx.x;
    if (bid < 8192) {   // cvt Q (bid<4096) or K
        const float* src = (bid < 4096) ? q : k;
        u16* dst = (bid < 4096) ? Qb : Kb;
        int i = (((bid & 4095) * 256) + tid) * 8;
        float4 a = *(const float4*)(src + i);
        float4 b2 = *(const float4*)(src + i + 4);
        union { ushort4 h[2]; s16x8 v; } r;
        r.h[0] = make_ushort4(f2bf(a.x), f2bf(a.y), f2bf(a.z), f2bf(a.w));
        r.h[1] = make_ushort4(f2bf(b2.x), f2bf(b2.y), f2bf(b2.z), f2bf(b2.w));
        *(s16x8*)(dst + i) = r.v;
    } else {            // trv tile
        int tt = bid - 8192;                 // 0..2047
        const int d0 = (tt & 7) * 64, j0 = ((tt >> 3) & 15) * 64, b = tt >> 7;
        const int tj = tid >> 2;
        const int td = (tid & 3) * 16;
        const float* src = v + ((size_t)b * S_ + j0 + tj) * D_ + d0 + td;
#pragma unroll
        for (int e = 0; e < 4; ++e) {
            float4 a = *(const float4*)(src + e * 4);
            *(ushort4*)(t + tj * TP + td + e * 4) =
                make_ushort4(f2bf(a.x), f2bf(a.y), f2bf(a.z), f2bf(a.w));
        }
        __syncthreads();
        const int dd = tid >> 2;
        const int jj = (tid & 3) * 16;
        u16* dstp = Vt + ((size_t)b * D_ + d0 + dd) * S_ + j0 + jj;
        u16 tmp[16];
#pragma unroll
        for (int e = 0; e < 16; ++e) tmp[e] = t[(jj + e) * TP + dd];
        *(s16x8*)dstp = *(s16x8*)tmp;
        *(s16x8*)(dstp + 8) = *(s16x8*)(tmp + 8);
    }
}

// swizzled LDS read: logical [row][col(64 bf16)] stored with byte ^= (row&7)<<4
__device__ __forceinline__ s16x8 frag_swz(const u16* lds, int row, int colbyte) {
    int off = row * 128 + (colbyte ^ ((row & 7) << 4));
    return *(const s16x8*)((const char*)lds + off);
}

// m97-style bf16 GEMM tile body (proven): 128x128, BK=64, global_load_lds + swizzle
__device__ __forceinline__ void gemm_body(const u16* ag, const u16* bg, int lda, int ldb,
                                          int nk, u16* lA, u16* lB, f32x4 acc[4][4],
                                          int tid) {
    const int lane = tid & 63, wid = tid >> 6;
    const int l8 = lane >> 3, l7 = lane & 7;
    const int cswz = (l7 ^ l8) * 8;
    const u16* ga[4];
    const u16* gb[4];
#pragma unroll
    for (int q2 = 0; q2 < 4; ++q2) {
        int seg = wid * 4 + q2;
        int row = seg * 8 + l8;
        ga[q2] = ag + (size_t)row * lda + cswz;
        gb[q2] = bg + (size_t)row * ldb + cswz;
    }
    const int wr = (wid >> 1) * 64, wc = (wid & 1) * 64;
    const int r15 = lane & 15;
    const int cb = (lane >> 4) * 16;

    for (int kk = 0; kk < nk; kk += 64) {
#pragma unroll
        for (int q2 = 0; q2 < 4; ++q2) {
            int seg = wid * 4 + q2;
            GLD16(ga[q2] + kk, lA + seg * 512);
            GLD16(gb[q2] + kk, lB + seg * 512);
        }
        __syncthreads();
#pragma unroll
        for (int ks = 0; ks < 2; ++ks) {
            s16x8 af[4], bf4[4];
#pragma unroll
            for (int m = 0; m < 4; ++m) af[m] = frag_swz(lA, wr + m * 16 + r15, ks * 64 + cb);
#pragma unroll
            for (int n = 0; n < 4; ++n) bf4[n] = frag_swz(lB, wc + n * 16 + r15, ks * 64 + cb);
#pragma unroll
            for (int m = 0; m < 4; ++m)
#pragma unroll
                for (int n = 0; n < 4; ++n)
                    acc[m][n] = __builtin_amdgcn_mfma_f32_16x16x32_bf16(af[m], bf4[n], acc[m][n], 0, 0, 0);
        }
        __syncthreads();
    }
}

// ===== qk3: QK^T tile GEMM + distance/mask marking + per-tile row stats =====
// Writes v = logits/sqrtD - (i-j) for valid, -1e30 for invalid, nothing for mi=0 rows.
// Stats st[b][kt][i] = (m_t, s_t): m_t = max(0, max valid v), s_t = sum exp(v - m_t).
__global__ __launch_bounds__(256) void qk3_kernel(const u16* __restrict__ Qb,
                                                  const u16* __restrict__ Kb,
                                                  const int* __restrict__ rep,
                                                  float* __restrict__ attn,
                                                  float2* __restrict__ st) {
    const int bid = blockIdx.x;
    const int xcd = bid & 7;
    const int w = bid >> 3;            // 0..71
    const int b = xcd * 2 + (w & 1);
    int p = w >> 1;                    // causal pair 0..35
    int qt = 0, tri = 0;
    while (p >= tri + qt + 1) { tri += qt + 1; ++qt; }
    const int kt = p - tri;

    __shared__ u16 lA[128 * 64];
    __shared__ u16 lB[128 * 64];
    __shared__ int lrepr[128];
    __shared__ int lrepc[128];
    __shared__ float lst[2][64][2][2];

    const int tid = threadIdx.x, lane = tid & 63, wid = tid >> 6;
    if (tid < 128) lrepr[tid] = rep[(size_t)b * S_ + qt * 128 + tid];
    else lrepc[tid - 128] = rep[(size_t)b * S_ + kt * 128 + (tid - 128)];

    f32x4 acc[4][4] = {};
    gemm_body(Qb + ((size_t)b * S_ + (size_t)qt * 128) * D_,
              Kb + ((size_t)b * S_ + (size_t)kt * 128) * D_,
              D_, D_, D_, lA, lB, acc, tid);

    const float scale = 0.04419417382415922f;  // 1/sqrt(512)
    const int wr = (wid >> 1) * 64, wc = (wid & 1) * 64;
    const int r15 = lane & 15, g4 = lane >> 4;
    size_t base = ((size_t)b * S_ + (size_t)qt * 128) * S_ + (size_t)kt * 128;

#pragma unroll
    for (int m = 0; m < 4; ++m)
#pragma unroll
        for (int r = 0; r < 4; ++r) {
            const int row = wr + m * 16 + g4 * 4 + r;
            const int gi = qt * 128 + row;
            const int im = lrepr[row];
            float vv[4];
            float mx = 0.0f;   // reference: masked entries contribute 0 to row max
#pragma unroll
            for (int n = 0; n < 4; ++n) {
                const int col = wc + n * 16 + r15;
                const int gj = kt * 128 + col;
                const bool val = im && (gj < gi) && (lrepc[col] != 0);
                float v = acc[m][n][r] * scale - (float)(gi - gj);
                vv[n] = val ? v : -1e30f;
                if (val) mx = fmaxf(mx, v);
            }
            if (im) {
#pragma unroll
                for (int n = 0; n < 4; ++n)
                    attn[base + (size_t)row * S_ + wc + n * 16 + r15] = vv[n];
            }
            // merge max across the 16 lanes (cols) of this row
#pragma unroll
            for (int off = 1; off < 16; off <<= 1)
                mx = fmaxf(mx, __shfl_xor(mx, off));
            float sm = 0.0f;
#pragma unroll
            for (int n = 0; n < 4; ++n)
                if (vv[n] > -1e29f) sm += __expf(vv[n] - mx);
#pragma unroll
            for (int off = 1; off < 16; off <<= 1)
                sm += __shfl_xor(sm, off);
            if (r15 == 0) {
                lst[wid >> 1][m * 16 + g4 * 4 + r][wid & 1][0] = mx;
                lst[wid >> 1][m * 16 + g4 * 4 + r][wid & 1][1] = sm;
            }
        }
    __syncthreads();
    if (tid < 128) {
        const int wr2 = tid >> 6, row = tid & 63;
        float m0 = lst[wr2][row][0][0], s0 = lst[wr2][row][0][1];
        float m1 = lst[wr2][row][1][0], s1 = lst[wr2][row][1][1];
        float M = fmaxf(m0, m1);
        float S = s0 * __expf(m0 - M) + s1 * __expf(m1 - M);
        const int gi = qt * 128 + wr2 * 64 + row;
        st[(((size_t)b * 8 + kt) << 10) + gi] = make_float2(M, S);
    }
}

// ===== fin: merge stats -> write final P fp32 (in-place) + PV MFMA -> out =====
// Block = (b, 16-row group). 1024 blocks, 256 thr (4 waves), wave d-slice = wid*128.
__global__ __launch_bounds__(256) void fin_kernel(const float2* __restrict__ st,
                                                  const int* __restrict__ rep,
                                                  const u16* __restrict__ Vt,
                                                  float* __restrict__ attn,
                                                  float* __restrict__ out) {
    const int bid = blockIdx.x;
    const int xcd = bid & 7, w = bid >> 3;        // w 0..127
    const int b = xcd * 2 + (w & 1);
    const int t = w >> 1;                         // 0..63
    const int qc = ((t & 7) << 3) | (t >> 3);     // permute: mix heavy/light blocks
    const int i0 = qc * 16;
    const int nct = (qc >> 3) + 1;                // valid 128-col chunks

    __shared__ u16 lP[16 * 128];                  // [row16][2 half][64], frag_swz layout
    __shared__ float lM[16], lI[16];
    __shared__ int lmi[16];

    const int tid = threadIdx.x, lane = tid & 63, wid = tid >> 6;
    const int r15 = lane & 15, g4 = lane >> 4;

    if (tid < 16) {
        const int gi = i0 + tid;
        float M = 0.0f, S = 0.0f;
        for (int kt = 0; kt < nct; ++kt) {
            float2 ms = st[(((size_t)b * 8 + kt) << 10) + gi];
            float Mn = fmaxf(M, ms.x);
            S = S * __expf(M - Mn) + ms.y * __expf(ms.x - Mn);
            M = Mn;
        }
        float denom = (S == 0.0f ? 1.0f : S) + 1e-20f;
        lM[tid] = M;
        lI[tid] = 1.0f / denom;
        lmi[tid] = rep[(size_t)b * S_ + gi];
    }
    __syncthreads();

    float* aw = attn + ((size_t)b * S_ + i0) * S_;
    const u16* vtb = Vt + (size_t)b * D_ * S_;
    const int row16 = tid >> 4, u = tid & 15;

    f32x4 acc[8] = {};
    for (int c = 0; c < 8; ++c) {
        if (c < nct) {
            __syncthreads();   // prior chunk's lP reads complete
            float pvv[8];
            if (lmi[row16]) {
                const float* src = aw + (size_t)row16 * S_ + c * 128 + u * 8;
                float4 x0 = *(const float4*)src;
                float4 x1 = *(const float4*)(src + 4);
                const float M = lM[row16], I = lI[row16];
                pvv[0] = __expf(x0.x - M) * I; pvv[1] = __expf(x0.y - M) * I;
                pvv[2] = __expf(x0.z - M) * I; pvv[3] = __expf(x0.w - M) * I;
                pvv[4] = __expf(x1.x - M) * I; pvv[5] = __expf(x1.y - M) * I;
                pvv[6] = __expf(x1.z - M) * I; pvv[7] = __expf(x1.w - M) * I;
            } else {
#pragma unroll
                for (int e = 0; e < 8; ++e) pvv[e] = 0.0f;
            }
            float* dst = aw + (size_t)row16 * S_ + c * 128 + u * 8;
            *(float4*)dst = make_float4(pvv[0], pvv[1], pvv[2], pvv[3]);
            *(float4*)(dst + 4) = make_float4(pvv[4], pvv[5], pvv[6], pvv[7]);
            {
                union { ushort4 h[2]; s16x8 v; } r;
                r.h[0] = make_ushort4(f2bf(pvv[0]), f2bf(pvv[1]), f2bf(pvv[2]), f2bf(pvv[3]));
                r.h[1] = make_ushort4(f2bf(pvv[4]), f2bf(pvv[5]), f2bf(pvv[6]), f2bf(pvv[7]));
                const int half = u >> 3, colb = (u & 7) * 16;
                *(s16x8*)((char*)lP + (row16 * 2 + half) * 128 + (colb ^ ((row16 & 7) << 4))) = r.v;
            }
            __syncthreads();   // P chunk staged
#pragma unroll
            for (int ks = 0; ks < 4; ++ks) {
                const int half = ks >> 1, colb = (ks & 1) * 64 + g4 * 16;
                s16x8 pa = *(const s16x8*)((const char*)lP +
                             (r15 * 2 + half) * 128 + (colb ^ ((r15 & 7) << 4)));
#pragma unroll
                for (int nf = 0; nf < 8; ++nf) {
                    s16x8 vb = *(const s16x8*)(vtb +
                        (size_t)(wid * 128 + nf * 16 + r15) * S_ + c * 128 + ks * 32 + g4 * 8);
                    acc[nf] = __builtin_amdgcn_mfma_f32_16x16x32_bf16(pa, vb, acc[nf], 0, 0, 0);
                }
            }
        } else {
            float* dst = aw + (size_t)row16 * S_ + c * 128 + u * 8;
            *(float4*)dst = make_float4(0.f, 0.f, 0.f, 0.f);
            *(float4*)(dst + 4) = make_float4(0.f, 0.f, 0.f, 0.f);
        }
    }

    float* ob = out + ((size_t)b * S_ + i0) * D_;
#pragma unroll
    for (int nf = 0; nf < 8; ++nf)
#pragma unroll
        for (int rg = 0; rg < 4; ++rg)
            ob[(size_t)(g4 * 4 + rg) * D_ + wid * 128 + nf * 16 + r15] = acc[nf][rg];
}

// ======================= legacy fallback path (no ws) =======================

union Frag { s16x8 v; uint2 u[2]; };

__device__ __forceinline__ s16x8 load_frag(const u16* lds, int row, int kq) {
    Frag f;
    const u16* p = lds + row * PITCH + kq;
    f.u[0] = *(const uint2*)p;
    f.u[1] = *(const uint2*)(p + 4);
    return f.v;
}

__device__ __forceinline__ void stage_granule(u16* lds, const float* src, int ldsrc, int g) {
    int row = g >> 2;
    int c8 = (g & 3) * 8;
    const float4* s = (const float4*)(src + (size_t)row * ldsrc + c8);
    float4 x0 = s[0], x1 = s[1];
    *(ushort4*)(lds + row * PITCH + c8) =
        make_ushort4(f2bf(x0.x), f2bf(x0.y), f2bf(x0.z), f2bf(x0.w));
    *(ushort4*)(lds + row * PITCH + c8 + 4) =
        make_ushort4(f2bf(x1.x), f2bf(x1.y), f2bf(x1.z), f2bf(x1.w));
}

__global__ __launch_bounds__(256) void qk_kernel(const float* __restrict__ q,
                                                 const float* __restrict__ k,
                                                 float* __restrict__ attn) {
    const int kt = blockIdx.x, qt = blockIdx.y, b = blockIdx.z;
    if (kt > qt) return;
    __shared__ u16 lA[TILE * PITCH];
    __shared__ u16 lB[TILE * PITCH];
    const int tid = threadIdx.x;
    const int lane = tid & 63;
    const int wid = tid >> 6;
    const int wr = (wid >> 1) * 64, wc = (wid & 1) * 64;
    const int r15 = lane & 15, kq = (lane >> 4) * 8;
    const float* qb = q + ((size_t)b * S_ + (size_t)qt * TILE) * D_;
    const float* kb = k + ((size_t)b * S_ + (size_t)kt * TILE) * D_;
    f32x4 acc[4][4] = {};
    for (int kk = 0; kk < D_; kk += BK) {
        __syncthreads();
        stage_granule(lA, qb + kk, D_, tid);
        stage_granule(lA, qb + kk, D_, tid + 256);
        stage_granule(lB, kb + kk, D_, tid);
        stage_granule(lB, kb + kk, D_, tid + 256);
        __syncthreads();
        s16x8 af[4], bf[4];
#pragma unroll
        for (int m = 0; m < 4; ++m) af[m] = load_frag(lA, wr + m * 16 + r15, kq);
#pragma unroll
        for (int n = 0; n < 4; ++n) bf[n] = load_frag(lB, wc + n * 16 + r15, kq);
#pragma unroll
        for (int m = 0; m < 4; ++m)
#pragma unroll
            for (int n = 0; n < 4; ++n)
                acc[m][n] = __builtin_amdgcn_mfma_f32_16x16x32_bf16(af[m], bf[n], acc[m][n], 0, 0, 0);
    }
    const float scale = 0.04419417382415922f;
    size_t base = ((size_t)b * S_ + (size_t)qt * TILE) * S_ + (size_t)kt * TILE;
    const int rr = (lane >> 4) * 4;
#pragma unroll
    for (int m = 0; m < 4; ++m)
#pragma unroll
        for (int n = 0; n < 4; ++n)
#pragma unroll
            for (int r = 0; r < 4; ++r)
                attn[base + (size_t)(wr + m * 16 + rr + r) * S_ + wc + n * 16 + r15] =
                    acc[m][n][r] * scale;
}

__global__ __launch_bounds__(256) void sm_kernel(const int* __restrict__ rep_mask,
                                                 float* __restrict__ attn) {
    const int i = blockIdx.x, b = blockIdx.y;
    const int tid = threadIdx.x;
    const int lane = tid & 63, wid = tid >> 6;
    float* row = attn + ((size_t)b * S_ + i) * S_;
    const int* rm = rep_mask + (size_t)b * S_;
    __shared__ float red[8];
    const int mi = rm[i];
    const int j0 = tid * 4;
    int4 m4 = ((const int4*)rm)[tid];
    float4 lv = make_float4(0.f, 0.f, 0.f, 0.f);
    if (mi != 0 && j0 < i) lv = *(const float4*)(row + j0);
    const int mv[4] = {m4.x, m4.y, m4.z, m4.w};
    const float lf[4] = {lv.x, lv.y, lv.z, lv.w};
    float vec[4];
    bool val[4];
    float mymax = 0.0f;
#pragma unroll
    for (int e = 0; e < 4; ++e) {
        int j = j0 + e;
        val[e] = (mi != 0) && (j < i) && (mv[e] != 0);
        vec[e] = lf[e] - (float)(i - j);
        if (val[e]) mymax = fmaxf(mymax, vec[e]);
    }
#pragma unroll
    for (int off = 32; off > 0; off >>= 1) mymax = fmaxf(mymax, __shfl_down(mymax, off));
    if (lane == 0) red[wid] = mymax;
    __syncthreads();
    const float m = fmaxf(fmaxf(red[0], red[1]), fmaxf(red[2], red[3]));
    float ex[4];
    float mysum = 0.0f;
#pragma unroll
    for (int e = 0; e < 4; ++e) {
        ex[e] = val[e] ? expf(vec[e] - m) : 0.0f;
        mysum += ex[e];
    }
#pragma unroll
    for (int off = 32; off > 0; off >>= 1) mysum += __shfl_down(mysum, off);
    if (lane == 0) red[4 + wid] = mysum;
    __syncthreads();
    const float ssum = red[4] + red[5] + red[6] + red[7];
    const float denom = ssum + (ssum == 0.0f ? 1.0f : 0.0f) + 1e-20f;
    const float inv = 1.0f / denom;
    *(float4*)(row + j0) = make_float4(ex[0] * inv, ex[1] * inv, ex[2] * inv, ex[3] * inv);
}

__global__ __launch_bounds__(256) void pv_kernel(const float* __restrict__ attn,
                                                 const float* __restrict__ v,
                                                 float* __restrict__ out) {
    const int dt = blockIdx.x, qt = blockIdx.y, b = blockIdx.z;
    __shared__ u16 lP[TILE * PITCH];
    __shared__ u16 lV[TILE * PITCH];
    const int tid = threadIdx.x;
    const int lane = tid & 63;
    const int wid = tid >> 6;
    const int wr = (wid >> 1) * 64, wc = (wid & 1) * 64;
    const int r15 = lane & 15, kq = (lane >> 4) * 8;
    const float* pb = attn + ((size_t)b * S_ + (size_t)qt * TILE) * S_;
    const float* vb = v + (size_t)b * S_ * D_ + (size_t)dt * TILE;
    const int vd0 = (tid & 31) * 4;
    const int vj0 = (tid >> 5) * 4;
    f32x4 acc[4][4] = {};
    const int nk = (qt + 1) * TILE;
    for (int kk = 0; kk < nk; kk += BK) {
        __syncthreads();
        stage_granule(lP, pb + kk, S_, tid);
        stage_granule(lP, pb + kk, S_, tid + 256);
        {
            const float* vs = vb + (size_t)(kk + vj0) * D_ + vd0;
            float4 r0 = *(const float4*)vs;
            float4 r1 = *(const float4*)(vs + D_);
            float4 r2 = *(const float4*)(vs + 2 * D_);
            float4 r3 = *(const float4*)(vs + 3 * D_);
            *(ushort4*)(lV + (vd0 + 0) * PITCH + vj0) = make_ushort4(f2bf(r0.x), f2bf(r1.x), f2bf(r2.x), f2bf(r3.x));
            *(ushort4*)(lV + (vd0 + 1) * PITCH + vj0) = make_ushort4(f2bf(r0.y), f2bf(r1.y), f2bf(r2.y), f2bf(r3.y));
            *(ushort4*)(lV + (vd0 + 2) * PITCH + vj0) = make_ushort4(f2bf(r0.z), f2bf(r1.z), f2bf(r2.z), f2bf(r3.z));
            *(ushort4*)(lV + (vd0 + 3) * PITCH + vj0) = make_ushort4(f2bf(r0.w), f2bf(r1.w), f2bf(r2.w), f2bf(r3.w));
        }
        __syncthreads();
        s16x8 af[4], bf[4];
#pragma unroll
        for (int m = 0; m < 4; ++m) af[m] = load_frag(lP, wr + m * 16 + r15, kq);
#pragma unroll
        for (int n = 0; n < 4; ++n) bf[n] = load_frag(lV, wc + n * 16 + r15, kq);
#pragma unroll
        for (int m = 0; m < 4; ++m)
#pragma unroll
            for (int n = 0; n < 4; ++n)
                acc[m][n] = __builtin_amdgcn_mfma_f32_16x16x32_bf16(af[m], bf[n], acc[m][n], 0, 0, 0);
    }
    size_t base = ((size_t)b * S_ + (size_t)qt * TILE) * D_ + (size_t)dt * TILE;
    const int rr = (lane >> 4) * 4;
#pragma unroll
    for (int m = 0; m < 4; ++m)
#pragma unroll
        for (int n = 0; n < 4; ++n)
#pragma unroll
            for (int r = 0; r < 4; ++r)
                out[base + (size_t)(wr + m * 16 + rr + r) * D_ + wc + n * 16 + r15] =
                    acc[m][n][r];
}

extern "C" void kernel_launch(void* const* d_in, const int* in_sizes, int n_in,
                              void* d_out, int out_size, void* d_ws, size_t ws_size,
                              hipStream_t stream) {
    const float* q = (const float*)d_in[0];
    const float* k = (const float*)d_in[1];
    const float* v = (const float*)d_in[2];
    const int* rep = (const int*)d_in[3];
    float* out = (float*)d_out;
    float* attn = out + (size_t)B_ * S_ * D_;   // second output region [B,S,S]

    const size_t nqk = (size_t)B_ * S_ * D_;    // 8.4M elems
    const size_t nst = (size_t)B_ * 8 * S_;     // stats entries (float2)
    const size_t need = 3 * nqk * sizeof(u16) + nst * sizeof(float2);  // 51.4 MB
    if (ws_size >= need) {
        u16* Qb = (u16*)d_ws;
        u16* Kb = Qb + nqk;
        u16* Vt = Kb + nqk;
        float2* st = (float2*)(Vt + nqk);
        prep_kernel<<<10240, 256, 0, stream>>>(q, k, v, Qb, Kb, Vt);
        qk3_kernel<<<8 * 72, 256, 0, stream>>>(Qb, Kb, rep, attn, st);
        fin_kernel<<<1024, 256, 0, stream>>>(st, rep, Vt, attn, out);
    } else {
        qk_kernel<<<dim3(S_ / TILE, S_ / TILE, B_), 256, 0, stream>>>(q, k, attn);
        sm_kernel<<<dim3(S_, B_), 256, 0, stream>>>(rep, attn);
        pv_kernel<<<dim3(D_ / TILE, S_ / TILE, B_), 256, 0, stream>>>(attn, v, out);
    }
}

// Round 8
// 89.975 us; speedup vs baseline: 1.8283x; 1.8283x over previous
//
#include <hip/hip_runtime.h>
#include <cstdint>

#define B_ 16
#define S_ 1024
#define D_ 512
#define TILE 128
#define BK 32
#define PITCH 36   // legacy-path LDS pitch

typedef float f32x4 __attribute__((ext_vector_type(4)));
typedef short s16x8 __attribute__((ext_vector_type(8)));
typedef unsigned short u16;
typedef unsigned int u32;

__device__ __forceinline__ u16 f2bf(float f) {
    u32 u = __builtin_bit_cast(u32, f);
    u += 0x7FFFu + ((u >> 16) & 1u);
    return (u16)(u >> 16);
}

#define GLD16(g, l) __builtin_amdgcn_global_load_lds( \
    (const __attribute__((address_space(1))) u32*)(g), \
    (__attribute__((address_space(3))) u32*)(l), 16, 0, 0)

// ===== prep: cvt(Q) + cvt(K) + transpose-cvt(V) in one launch (round-7 proven) =====
#define TP 66
__global__ __launch_bounds__(256) void prep_kernel(const float* __restrict__ q,
                                                   const float* __restrict__ k,
                                                   const float* __restrict__ v,
                                                   u16* __restrict__ Qb,
                                                   u16* __restrict__ Kb,
                                                   u16* __restrict__ Vt) {
    __shared__ u16 t[64 * TP];
    const int bid = blockIdx.x;
    const int tid = threadIdx.x;
    if (bid < 8192) {   // cvt Q (bid<4096) or K
        const float* src = (bid < 4096) ? q : k;
        u16* dst = (bid < 4096) ? Qb : Kb;
        int i = (((bid & 4095) * 256) + tid) * 8;
        float4 a = *(const float4*)(src + i);
        float4 b2 = *(const float4*)(src + i + 4);
        union { ushort4 h[2]; s16x8 v; } r;
        r.h[0] = make_ushort4(f2bf(a.x), f2bf(a.y), f2bf(a.z), f2bf(a.w));
        r.h[1] = make_ushort4(f2bf(b2.x), f2bf(b2.y), f2bf(b2.z), f2bf(b2.w));
        *(s16x8*)(dst + i) = r.v;
    } else {            // trv tile
        int tt = bid - 8192;                 // 0..2047
        const int d0 = (tt & 7) * 64, j0 = ((tt >> 3) & 15) * 64, b = tt >> 7;
        const int tj = tid >> 2;
        const int td = (tid & 3) * 16;
        const float* src = v + ((size_t)b * S_ + j0 + tj) * D_ + d0 + td;
#pragma unroll
        for (int e = 0; e < 4; ++e) {
            float4 a = *(const float4*)(src + e * 4);
            *(ushort4*)(t + tj * TP + td + e * 4) =
                make_ushort4(f2bf(a.x), f2bf(a.y), f2bf(a.z), f2bf(a.w));
        }
        __syncthreads();
        const int dd = tid >> 2;
        const int jj = (tid & 3) * 16;
        u16* dstp = Vt + ((size_t)b * D_ + d0 + dd) * S_ + j0 + jj;
        u16 tmp[16];
#pragma unroll
        for (int e = 0; e < 16; ++e) tmp[e] = t[(jj + e) * TP + dd];
        *(s16x8*)dstp = *(s16x8*)tmp;
        *(s16x8*)(dstp + 8) = *(s16x8*)(tmp + 8);
    }
}

// swizzled LDS read: logical [row][col(64 bf16)] stored with byte ^= (row&7)<<4
__device__ __forceinline__ s16x8 frag_swz(const u16* lds, int row, int colbyte) {
    int off = row * 128 + (colbyte ^ ((row & 7) << 4));
    return *(const s16x8*)((const char*)lds + off);
}

// m97-style bf16 GEMM tile body (proven): 128x128, BK=64, global_load_lds + swizzle
__device__ __forceinline__ void gemm_body(const u16* ag, const u16* bg, int lda, int ldb,
                                          int nk, u16* lA, u16* lB, f32x4 acc[4][4],
                                          int tid) {
    const int lane = tid & 63, wid = tid >> 6;
    const int l8 = lane >> 3, l7 = lane & 7;
    const int cswz = (l7 ^ l8) * 8;
    const u16* ga[4];
    const u16* gb[4];
#pragma unroll
    for (int q2 = 0; q2 < 4; ++q2) {
        int seg = wid * 4 + q2;
        int row = seg * 8 + l8;
        ga[q2] = ag + (size_t)row * lda + cswz;
        gb[q2] = bg + (size_t)row * ldb + cswz;
    }
    const int wr = (wid >> 1) * 64, wc = (wid & 1) * 64;
    const int r15 = lane & 15;
    const int cb = (lane >> 4) * 16;

    for (int kk = 0; kk < nk; kk += 64) {
#pragma unroll
        for (int q2 = 0; q2 < 4; ++q2) {
            int seg = wid * 4 + q2;
            GLD16(ga[q2] + kk, lA + seg * 512);
            GLD16(gb[q2] + kk, lB + seg * 512);
        }
        __syncthreads();
#pragma unroll
        for (int ks = 0; ks < 2; ++ks) {
            s16x8 af[4], bf4[4];
#pragma unroll
            for (int m = 0; m < 4; ++m) af[m] = frag_swz(lA, wr + m * 16 + r15, ks * 64 + cb);
#pragma unroll
            for (int n = 0; n < 4; ++n) bf4[n] = frag_swz(lB, wc + n * 16 + r15, ks * 64 + cb);
#pragma unroll
            for (int m = 0; m < 4; ++m)
#pragma unroll
                for (int n = 0; n < 4; ++n)
                    acc[m][n] = __builtin_amdgcn_mfma_f32_16x16x32_bf16(af[m], bf4[n], acc[m][n], 0, 0, 0);
        }
        __syncthreads();
    }
}

// QK^T: 1D grid, XCD-chunked, LPT (heavy pairs first); skips stores for masked rows.
__global__ __launch_bounds__(256) void qk2_kernel(const u16* __restrict__ Qb,
                                                  const u16* __restrict__ Kb,
                                                  const int* __restrict__ rep,
                                                  float* __restrict__ attn) {
    const int bid = blockIdx.x;
    const int xcd = bid & 7;
    const int w = bid >> 3;            // 0..71
    const int b = xcd * 2 + (w & 1);
    int p = 35 - (w >> 1);             // LPT: large qt first
    int qt = 0, tri = 0;
    while (p >= tri + qt + 1) { tri += qt + 1; ++qt; }
    const int kt = p - tri;

    __shared__ u16 lA[128 * 64];
    __shared__ u16 lB[128 * 64];
    __shared__ int lrepr[128];
    const int tid = threadIdx.x, lane = tid & 63, wid = tid >> 6;
    if (tid < 128) lrepr[tid] = rep[(size_t)b * S_ + qt * 128 + tid];

    f32x4 acc[4][4] = {};
    gemm_body(Qb + ((size_t)b * S_ + (size_t)qt * 128) * D_,
              Kb + ((size_t)b * S_ + (size_t)kt * 128) * D_,
              D_, D_, D_, lA, lB, acc, tid);
    const float scale = 0.04419417382415922f;  // 1/sqrt(512)
    const int wr = (wid >> 1) * 64, wc = (wid & 1) * 64;
    const int r15 = lane & 15, rr = (lane >> 4) * 4;
    size_t base = ((size_t)b * S_ + (size_t)qt * 128) * S_ + (size_t)kt * 128;
#pragma unroll
    for (int m = 0; m < 4; ++m)
#pragma unroll
        for (int r = 0; r < 4; ++r) {
            const int row = wr + m * 16 + rr + r;
            if (lrepr[row]) {   // sm never reads rows with rep==0
#pragma unroll
                for (int n = 0; n < 4; ++n)
                    attn[base + (size_t)row * S_ + wc + n * 16 + r15] =
                        acc[m][n][r] * scale;
            }
        }
}

// PV from bf16 Pb (proven round-3 structure), LPT qt-descending
__global__ __launch_bounds__(256) void pv2_kernel(const u16* __restrict__ Pb,
                                                  const u16* __restrict__ Vt,
                                                  float* __restrict__ out) {
    const int bid = blockIdx.x;
    const int xcd = bid & 7;
    const int w = bid >> 3;
    const int b = xcd * 2 + (w & 1);
    const int r = w >> 1;
    const int dt = r & 3, qt = 7 - (r >> 2);   // heavy qt first

    __shared__ u16 lA[128 * 64];
    __shared__ u16 lB[128 * 64];
    const int tid = threadIdx.x, lane = tid & 63, wid = tid >> 6;
    f32x4 acc[4][4] = {};
    gemm_body(Pb + ((size_t)b * S_ + (size_t)qt * 128) * S_,
              Vt + ((size_t)b * D_ + (size_t)dt * 128) * S_,
              S_, S_, (qt + 1) * 128, lA, lB, acc, tid);
    const int wr = (wid >> 1) * 64, wc = (wid & 1) * 64;
    const int r15 = lane & 15, rr = (lane >> 4) * 4;
    size_t base = ((size_t)b * S_ + (size_t)qt * 128) * D_ + (size_t)dt * 128;
#pragma unroll
    for (int m = 0; m < 4; ++m)
#pragma unroll
        for (int n = 0; n < 4; ++n)
#pragma unroll
            for (int rg = 0; rg < 4; ++rg)
                out[base + (size_t)(wr + m * 16 + rr + rg) * D_ + wc + n * 16 + r15] =
                    acc[m][n][rg];
}

// ------------- masked softmax per row (in-place; bf16 P to ws) — round-3 proven -------------
__global__ __launch_bounds__(256) void sm_kernel(const int* __restrict__ rep_mask,
                                                 float* __restrict__ attn,
                                                 u16* __restrict__ pb) {
    const int i = blockIdx.x, b = blockIdx.y;
    const int tid = threadIdx.x;
    const int lane = tid & 63, wid = tid >> 6;
    float* row = attn + ((size_t)b * S_ + i) * S_;
    const int* rm = rep_mask + (size_t)b * S_;
    __shared__ float red[8];

    const int mi = rm[i];
    const int j0 = tid * 4;
    int4 m4 = ((const int4*)rm)[tid];
    float4 lv = make_float4(0.f, 0.f, 0.f, 0.f);
    if (mi != 0 && j0 < i) lv = *(const float4*)(row + j0);

    const int mv[4] = {m4.x, m4.y, m4.z, m4.w};
    const float lf[4] = {lv.x, lv.y, lv.z, lv.w};
    float vec[4];
    bool val[4];
    float mymax = 0.0f;  // masked entries contribute 0 to the max (reference semantics)
#pragma unroll
    for (int e = 0; e < 4; ++e) {
        int j = j0 + e;
        val[e] = (mi != 0) && (j < i) && (mv[e] != 0);
        vec[e] = lf[e] - (float)(i - j);
        if (val[e]) mymax = fmaxf(mymax, vec[e]);
    }
#pragma unroll
    for (int off = 32; off > 0; off >>= 1) mymax = fmaxf(mymax, __shfl_down(mymax, off));
    if (lane == 0) red[wid] = mymax;
    __syncthreads();
    const float m = fmaxf(fmaxf(red[0], red[1]), fmaxf(red[2], red[3]));

    float ex[4];
    float mysum = 0.0f;
#pragma unroll
    for (int e = 0; e < 4; ++e) {
        ex[e] = val[e] ? expf(vec[e] - m) : 0.0f;
        mysum += ex[e];
    }
#pragma unroll
    for (int off = 32; off > 0; off >>= 1) mysum += __shfl_down(mysum, off);
    if (lane == 0) red[4 + wid] = mysum;
    __syncthreads();
    const float ssum = red[4] + red[5] + red[6] + red[7];
    const float denom = ssum + (ssum == 0.0f ? 1.0f : 0.0f) + 1e-20f;
    const float inv = 1.0f / denom;
    float4 o = make_float4(ex[0] * inv, ex[1] * inv, ex[2] * inv, ex[3] * inv);
    *(float4*)(row + j0) = o;   // every position written -> no poison leaks
    if (pb != nullptr && j0 <= (i | 127)) {  // bf16 copy for PV, causal tiles only
        u16* pr = pb + ((size_t)b * S_ + i) * S_ + j0;
        *(ushort4*)pr = make_ushort4(f2bf(o.x), f2bf(o.y), f2bf(o.z), f2bf(o.w));
    }
}

// ======================= legacy fallback path (no ws) =======================

union Frag { s16x8 v; uint2 u[2]; };

__device__ __forceinline__ s16x8 load_frag(const u16* lds, int row, int kq) {
    Frag f;
    const u16* p = lds + row * PITCH + kq;
    f.u[0] = *(const uint2*)p;
    f.u[1] = *(const uint2*)(p + 4);
    return f.v;
}

__device__ __forceinline__ void stage_granule(u16* lds, const float* src, int ldsrc, int g) {
    int row = g >> 2;
    int c8 = (g & 3) * 8;
    const float4* s = (const float4*)(src + (size_t)row * ldsrc + c8);
    float4 x0 = s[0], x1 = s[1];
    *(ushort4*)(lds + row * PITCH + c8) =
        make_ushort4(f2bf(x0.x), f2bf(x0.y), f2bf(x0.z), f2bf(x0.w));
    *(ushort4*)(lds + row * PITCH + c8 + 4) =
        make_ushort4(f2bf(x1.x), f2bf(x1.y), f2bf(x1.z), f2bf(x1.w));
}

__global__ __launch_bounds__(256) void qk_kernel(const float* __restrict__ q,
                                                 const float* __restrict__ k,
                                                 float* __restrict__ attn) {
    const int kt = blockIdx.x, qt = blockIdx.y, b = blockIdx.z;
    if (kt > qt) return;
    __shared__ u16 lA[TILE * PITCH];
    __shared__ u16 lB[TILE * PITCH];
    const int tid = threadIdx.x;
    const int lane = tid & 63;
    const int wid = tid >> 6;
    const int wr = (wid >> 1) * 64, wc = (wid & 1) * 64;
    const int r15 = lane & 15, kq = (lane >> 4) * 8;
    const float* qb = q + ((size_t)b * S_ + (size_t)qt * TILE) * D_;
    const float* kb = k + ((size_t)b * S_ + (size_t)kt * TILE) * D_;
    f32x4 acc[4][4] = {};
    for (int kk = 0; kk < D_; kk += BK) {
        __syncthreads();
        stage_granule(lA, qb + kk, D_, tid);
        stage_granule(lA, qb + kk, D_, tid + 256);
        stage_granule(lB, kb + kk, D_, tid);
        stage_granule(lB, kb + kk, D_, tid + 256);
        __syncthreads();
        s16x8 af[4], bf[4];
#pragma unroll
        for (int m = 0; m < 4; ++m) af[m] = load_frag(lA, wr + m * 16 + r15, kq);
#pragma unroll
        for (int n = 0; n < 4; ++n) bf[n] = load_frag(lB, wc + n * 16 + r15, kq);
#pragma unroll
        for (int m = 0; m < 4; ++m)
#pragma unroll
            for (int n = 0; n < 4; ++n)
                acc[m][n] = __builtin_amdgcn_mfma_f32_16x16x32_bf16(af[m], bf[n], acc[m][n], 0, 0, 0);
    }
    const float scale = 0.04419417382415922f;
    size_t base = ((size_t)b * S_ + (size_t)qt * TILE) * S_ + (size_t)kt * TILE;
    const int rr = (lane >> 4) * 4;
#pragma unroll
    for (int m = 0; m < 4; ++m)
#pragma unroll
        for (int n = 0; n < 4; ++n)
#pragma unroll
            for (int r = 0; r < 4; ++r)
                attn[base + (size_t)(wr + m * 16 + rr + r) * S_ + wc + n * 16 + r15] =
                    acc[m][n][r] * scale;
}

__global__ __launch_bounds__(256) void pv_kernel(const float* __restrict__ attn,
                                                 const float* __restrict__ v,
                                                 float* __restrict__ out) {
    const int dt = blockIdx.x, qt = blockIdx.y, b = blockIdx.z;
    __shared__ u16 lP[TILE * PITCH];
    __shared__ u16 lV[TILE * PITCH];
    const int tid = threadIdx.x;
    const int lane = tid & 63;
    const int wid = tid >> 6;
    const int wr = (wid >> 1) * 64, wc = (wid & 1) * 64;
    const int r15 = lane & 15, kq = (lane >> 4) * 8;
    const float* pb = attn + ((size_t)b * S_ + (size_t)qt * TILE) * S_;
    const float* vb = v + (size_t)b * S_ * D_ + (size_t)dt * TILE;
    const int vd0 = (tid & 31) * 4;
    const int vj0 = (tid >> 5) * 4;
    f32x4 acc[4][4] = {};
    const int nk = (qt + 1) * TILE;
    for (int kk = 0; kk < nk; kk += BK) {
        __syncthreads();
        stage_granule(lP, pb + kk, S_, tid);
        stage_granule(lP, pb + kk, S_, tid + 256);
        {
            const float* vs = vb + (size_t)(kk + vj0) * D_ + vd0;
            float4 r0 = *(const float4*)vs;
            float4 r1 = *(const float4*)(vs + D_);
            float4 r2 = *(const float4*)(vs + 2 * D_);
            float4 r3 = *(const float4*)(vs + 3 * D_);
            *(ushort4*)(lV + (vd0 + 0) * PITCH + vj0) = make_ushort4(f2bf(r0.x), f2bf(r1.x), f2bf(r2.x), f2bf(r3.x));
            *(ushort4*)(lV + (vd0 + 1) * PITCH + vj0) = make_ushort4(f2bf(r0.y), f2bf(r1.y), f2bf(r2.y), f2bf(r3.y));
            *(ushort4*)(lV + (vd0 + 2) * PITCH + vj0) = make_ushort4(f2bf(r0.z), f2bf(r1.z), f2bf(r2.z), f2bf(r3.z));
            *(ushort4*)(lV + (vd0 + 3) * PITCH + vj0) = make_ushort4(f2bf(r0.w), f2bf(r1.w), f2bf(r2.w), f2bf(r3.w));
        }
        __syncthreads();
        s16x8 af[4], bf[4];
#pragma unroll
        for (int m = 0; m < 4; ++m) af[m] = load_frag(lP, wr + m * 16 + r15, kq);
#pragma unroll
        for (int n = 0; n < 4; ++n) bf[n] = load_frag(lV, wc + n * 16 + r15, kq);
#pragma unroll
        for (int m = 0; m < 4; ++m)
#pragma unroll
            for (int n = 0; n < 4; ++n)
                acc[m][n] = __builtin_amdgcn_mfma_f32_16x16x32_bf16(af[m], bf[n], acc[m][n], 0, 0, 0);
    }
    size_t base = ((size_t)b * S_ + (size_t)qt * TILE) * D_ + (size_t)dt * TILE;
    const int rr = (lane >> 4) * 4;
#pragma unroll
    for (int m = 0; m < 4; ++m)
#pragma unroll
        for (int n = 0; n < 4; ++n)
#pragma unroll
            for (int r = 0; r < 4; ++r)
                out[base + (size_t)(wr + m * 16 + rr + r) * D_ + wc + n * 16 + r15] =
                    acc[m][n][r];
}

extern "C" void kernel_launch(void* const* d_in, const int* in_sizes, int n_in,
                              void* d_out, int out_size, void* d_ws, size_t ws_size,
                              hipStream_t stream) {
    const float* q = (const float*)d_in[0];
    const float* k = (const float*)d_in[1];
    const float* v = (const float*)d_in[2];
    const int* rep = (const int*)d_in[3];
    float* out = (float*)d_out;
    float* attn = out + (size_t)B_ * S_ * D_;   // second output region [B,S,S]

    const size_t nqk = (size_t)B_ * S_ * D_;           // 8.4M elems per tensor
    const size_t need = 3 * nqk * sizeof(u16);         // Qb + Kb + Vt = 50.3 MB
    if (ws_size >= need) {
        u16* Qb = (u16*)d_ws;
        u16* Kb = Qb + nqk;
        u16* Vt = Kb + nqk;
        u16* Pb = (u16*)d_ws;   // aliases Qb+Kb (exactly B*S*S bf16); dead after qk2
        prep_kernel<<<10240, 256, 0, stream>>>(q, k, v, Qb, Kb, Vt);
        qk2_kernel<<<8 * 72, 256, 0, stream>>>(Qb, Kb, rep, attn);
        sm_kernel<<<dim3(S_, B_), 256, 0, stream>>>(rep, attn, Pb);
        pv2_kernel<<<8 * 64, 256, 0, stream>>>(Pb, Vt, out);
    } else {
        qk_kernel<<<dim3(S_ / TILE, S_ / TILE, B_), 256, 0, stream>>>(q, k, attn);
        sm_kernel<<<dim3(S_, B_), 256, 0, stream>>>(rep, attn, nullptr);
        pv_kernel<<<dim3(D_ / TILE, S_ / TILE, B_), 256, 0, stream>>>(attn, v, out);
    }
}